// Round 6
// baseline (132.545 us; speedup 1.0000x reference)
//
#include <hip/hip_runtime.h>
#include <hip/hip_bf16.h>

typedef __bf16 bf16x8 __attribute__((ext_vector_type(8)));
typedef unsigned short u16x8 __attribute__((ext_vector_type(8)));
typedef unsigned int u32x2 __attribute__((ext_vector_type(2)));
typedef float f32x4 __attribute__((ext_vector_type(4)));
typedef unsigned short u16;

constexpr int DIMc = 256, Tt = 2048, Dd = 64;

// ws layout (u16 units) — ALL fragment-ready, linear (global loads: no banks):
//   CbF[1024][64] @0     : bf16(-2*c), code-major rows                = 128 KB
//   CN[1024] f32  @65536 : ||c||^2 (exact partial-sum tree)           =   4 KB
//   WinT[64][256] @67584 : bf16(Win^T), row d = encode A-row          =  32 KB
//   WoX[256][64]  @83968 : bf16(Wout^T), row c = decode A-row         =  32 KB
#define CBF_U  0
#define CN_U   65536
#define WINT_U 67584
#define WOX_U  83968

__device__ __forceinline__ u16 f2b(float f) {   // RNE float->bf16 bits
  unsigned u = __float_as_uint(f);
  return (u16)((u + 0x7FFFu + ((u >> 16) & 1u)) >> 16);
}
__device__ __forceinline__ float b2f(u16 v) {
  return __uint_as_float(((unsigned)v) << 16);
}
__device__ __forceinline__ unsigned f2b2(float a, float b) {  // packed RNE pair (low=a)
  return (unsigned)f2b(a) | ((unsigned)f2b(b) << 16);
}
__device__ __forceinline__ f32x4 mfma16(u16x8 a, u16x8 b, f32x4 c) {
  return __builtin_amdgcn_mfma_f32_16x16x32_bf16(
      __builtin_bit_cast(bf16x8, a), __builtin_bit_cast(bf16x8, b), c, 0, 0, 0);
}

// Prep: all fp32->bf16 weight conversion + transposition done ONCE.
__global__ void nsvq_prep(const float* __restrict__ cb, const float* __restrict__ Win,
                          const float* __restrict__ Wout, u16* __restrict__ wsu) {
  const int g = blockIdx.x * 256 + threadIdx.x;   // 64 blocks -> 16384 threads
  {  // CbF: 4 values/thread, value = bf16(-2c); row k is MFMA-A fragment-ready
    const int k = g >> 4, j = (g & 15) << 2;
    float4 v = *(const float4*)(cb + k * 64 + j);
    u16* row = wsu + CBF_U + k * 64 + j;
    row[0] = f2b(-2.f * v.x); row[1] = f2b(-2.f * v.y);
    row[2] = f2b(-2.f * v.z); row[3] = f2b(-2.f * v.w);
  }
  if (g < 1024) {  // CN: exact partial-sum tree (bit-stable across rounds)
    const float* cr = cb + g * 64;
    float p[4];
    #pragma unroll
    for (int q = 0; q < 4; ++q) {
      float4 a0 = ((const float4*)(cr + q * 8))[0],      a1 = ((const float4*)(cr + q * 8))[1];
      float4 a2 = ((const float4*)(cr + 32 + q * 8))[0], a3 = ((const float4*)(cr + 32 + q * 8))[1];
      float pA = fmaf(a0.w, a0.w, fmaf(a0.z, a0.z, fmaf(a0.y, a0.y, a0.x * a0.x)));
      float pB = fmaf(a1.w, a1.w, fmaf(a1.z, a1.z, fmaf(a1.y, a1.y, a1.x * a1.x)));
      float pC = fmaf(a2.w, a2.w, fmaf(a2.z, a2.z, fmaf(a2.y, a2.y, a2.x * a2.x)));
      float pD = fmaf(a3.w, a3.w, fmaf(a3.z, a3.z, fmaf(a3.y, a3.y, a3.x * a3.x)));
      p[q] = (pA + pB) + (pC + pD);
    }
    ((float*)(wsu + CN_U))[g] = (p[0] + p[1]) + (p[2] + p[3]);
  }
  {  // WinT: [d][c] linear
    const int d = g >> 8, c = g & 255;
    wsu[WINT_U + d * 256 + c] = f2b(Win[c * 64 + d]);
  }
  {  // WoX: [c][d] linear
    const int c = g >> 6, d = g & 63;
    wsu[WOX_U + c * 64 + d] = f2b(Wout[d * 256 + c]);
  }
}

// Main: block = 32 tokens, 128 threads (2 waves), grid 1024.
// LDS: Xt[32][64] bf16 swz (4 KB) + mnp[2][32] f32 (256 B) = 4352 B ->
// residency is VGPR/wave-slot-capped (~5-6 waves/SIMD), not LDS-capped.
// Weights are read as 16B fragments straight from L2-resident ws. 2 barriers.
__global__ __launch_bounds__(128, 5) void nsvq_main(
    const float* __restrict__ in, const float* __restrict__ rnd,
    const float* __restrict__ bin, const float* __restrict__ bout,
    const u16* __restrict__ wsu, float* __restrict__ out) {
  __shared__ u16 sm[2176];
  u16* const Xt   = sm;                     // [32][64] bf16 x (later q), swz
  float* const mnp = (float*)(sm + 2048);   // [2][32] per-wave code-slice mins

  const int tid  = threadIdx.x;
  const int lane = tid & 63;
  const int w    = tid >> 6;                // 0..1
  const int quad = lane >> 4, col = lane & 15;
  const int b    = blockIdx.x >> 6;         // 16 batches x 64 token-tiles
  const int t0   = (blockIdx.x & 63) << 5;
  const int myt  = w * 16 + col;            // own token row in block (0..31)

  // ---- encode B-fragments straight from global (own token; 64B-granule) ----
  u16x8 Bf[8];
  const float* ibase = in + (size_t)b * DIMc * Tt + t0 + myt;
  #pragma unroll
  for (int kt = 0; kt < 8; ++kt) {
    float v[8];
    #pragma unroll
    for (int j = 0; j < 8; ++j) v[j] = ibase[(size_t)(kt * 32 + quad * 8 + j) * Tt];
    u16x8 pk;
    #pragma unroll
    for (int j = 0; j < 8; ++j) pk[j] = f2b(v[j]);
    Bf[kt] = pk;
  }
  // ---- rr2: load rnd in acc-fragment layout, square-reduce, DISCARD regs ----
  const float* rbase = rnd + ((size_t)b * Tt + t0 + myt) * Dd + quad * 4;
  float rr2v = 0.f;
  #pragma unroll
  for (int mt = 0; mt < 4; ++mt) {
    float4 r = *(const float4*)(rbase + mt * 16);
    rr2v = fmaf(r.x, r.x, rr2v); rr2v = fmaf(r.y, r.y, rr2v);
    rr2v = fmaf(r.z, r.z, rr2v); rr2v = fmaf(r.w, r.w, rr2v);
  }
  rr2v += __shfl_xor(rr2v, 16);
  rr2v += __shfl_xor(rr2v, 32);             // full ||rnd||^2, replicated over quads

  // ---- encode: X^T = WinT · In, acc init = bin; A-fragments from L2 ws ----
  const u16* wsWin = wsu + WINT_U;
  f32x4 acc[4];
  #pragma unroll
  for (int mt = 0; mt < 4; ++mt) {
    float4 bi = *(const float4*)(bin + mt * 16 + quad * 4);
    f32x4 a = {bi.x, bi.y, bi.z, bi.w};
    const int d = mt * 16 + col;
    #pragma unroll
    for (int kt = 0; kt < 8; ++kt) {
      u16x8 A = *(const u16x8*)(wsWin + d * 256 + kt * 32 + quad * 8);
      a = mfma16(A, Bf[kt], a);
    }
    acc[mt] = a;
  }
  float x2v = 0.f;
  #pragma unroll
  for (int mt = 0; mt < 4; ++mt) {
    #pragma unroll
    for (int r = 0; r < 4; ++r) x2v = fmaf(acc[mt][r], acc[mt][r], x2v);
    u32x2 px = { f2b2(acc[mt][0], acc[mt][1]), f2b2(acc[mt][2], acc[mt][3]) };
    const int bk  = mt * 2 + (quad >> 1);
    const int off = myt * 64 + ((bk ^ (myt & 7)) << 3) + (quad & 1) * 4;
    *(u32x2*)(Xt + off) = px;
  }
  x2v += __shfl_xor(x2v, 16);
  x2v += __shfl_xor(x2v, 32);
  __syncthreads();   // Xt(x) ready for cross-wave reads

  // ---- distances: wave-private 512-code slice; fragment-ready CbF from L2 ----
  u16x8 Xa[2], Xb[2];
  #pragma unroll
  for (int nt = 0; nt < 2; ++nt) {
    const int tr = nt * 16 + col;
    Xa[nt] = *(const u16x8*)(Xt + tr * 64 + ((quad ^ (tr & 7)) << 3));
    Xb[nt] = *(const u16x8*)(Xt + tr * 64 + (((4 + quad) ^ (tr & 7)) << 3));
  }
  float minv[2] = {3.4e38f, 3.4e38f};
  const u16* cwf   = wsu + CBF_U + (size_t)(w * 512) * 64;
  const float* cnp = (const float*)(wsu + CN_U) + w * 512;
  #pragma unroll 4
  for (int mi = 0; mi < 32; ++mi) {
    u16x8 A0 = *(const u16x8*)(cwf + (mi * 16 + col) * 64 + quad * 8);
    u16x8 A1 = *(const u16x8*)(cwf + (mi * 16 + col) * 64 + 32 + quad * 8);
    f32x4 cn4 = *(const f32x4*)(cnp + mi * 16 + quad * 4);
    #pragma unroll
    for (int nt = 0; nt < 2; ++nt) {
      f32x4 a = mfma16(A0, Xa[nt], cn4);    // c^2 + x·(-2c)
      a = mfma16(A1, Xb[nt], a);
      #pragma unroll
      for (int r = 0; r < 4; ++r) minv[nt] = fminf(minv[nt], a[r]);
    }
  }
  #pragma unroll
  for (int nt = 0; nt < 2; ++nt) {
    float m = minv[nt];
    m = fminf(m, __shfl_xor(m, 16));
    m = fminf(m, __shfl_xor(m, 32));
    mnp[w * 32 + nt * 16 + col] = m;        // all quads write same value
  }
  __syncthreads();   // mnp ready; all Xt(x) reads complete

  // ---- q = x + sc*rnd in registers (reload rnd; acc layout); store q to Xt ----
  float mv = fminf(mnp[myt], mnp[32 + myt]);
  float r2  = fmaxf(x2v + mv, 0.f);                 // ||x - hard||^2
  float scv = sqrtf(r2) / (sqrtf(rr2v) + 1e-12f);   // own token's scale
  #pragma unroll
  for (int mt = 0; mt < 4; ++mt) {
    float4 r = *(const float4*)(rbase + mt * 16);
    float q0 = fmaf(scv, r.x, acc[mt][0]);
    float q1 = fmaf(scv, r.y, acc[mt][1]);
    float q2 = fmaf(scv, r.z, acc[mt][2]);
    float q3 = fmaf(scv, r.w, acc[mt][3]);
    u32x2 pq = { f2b2(q0, q1), f2b2(q2, q3) };
    const int bk  = mt * 2 + (quad >> 1);
    const int off = myt * 64 + ((bk ^ (myt & 7)) << 3) + (quad & 1) * 4;
    *(u32x2*)(Xt + off) = pq;               // own row; same-wave LDS order suffices
  }

  // ---- decode: out = WoX · q, acc init = bout; A-fragments from L2 ws ----
  u16x8 Q0 = *(const u16x8*)(Xt + myt * 64 + ((quad ^ (myt & 7)) << 3));
  u16x8 Q1 = *(const u16x8*)(Xt + myt * 64 + (((4 + quad) ^ (myt & 7)) << 3));
  const u16* wsWo = wsu + WOX_U;
  float* ob0 = out + (size_t)b * DIMc * Tt + t0 + myt;
  #pragma unroll
  for (int mt = 0; mt < 16; ++mt) {
    const int c = mt * 16 + col;
    u16x8 A0 = *(const u16x8*)(wsWo + c * 64 + quad * 8);
    u16x8 A1 = *(const u16x8*)(wsWo + c * 64 + 32 + quad * 8);
    float4 bo = *(const float4*)(bout + mt * 16 + quad * 4);
    f32x4 a = {bo.x, bo.y, bo.z, bo.w};
    a = mfma16(A0, Q0, a);
    a = mfma16(A1, Q1, a);
    float* ob = ob0 + (size_t)(mt * 16 + quad * 4) * Tt;
    #pragma unroll
    for (int r = 0; r < 4; ++r) ob[(size_t)r * Tt] = a[r];
  }
}

extern "C" void kernel_launch(void* const* d_in, const int* in_sizes, int n_in,
                              void* d_out, int out_size, void* d_ws, size_t ws_size,
                              hipStream_t stream) {
  const float *in = nullptr, *cbp = nullptr, *rnd = nullptr, *bin = nullptr, *bout = nullptr;
  const float* w16[2] = {nullptr, nullptr}; int nw = 0;
  for (int i = 0; i < n_in; ++i) {
    switch (in_sizes[i]) {
      case 8388608: in  = (const float*)d_in[i]; break;
      case 65536:   cbp = (const float*)d_in[i]; break;
      case 2097152: rnd = (const float*)d_in[i]; break;
      case 64:      bin = (const float*)d_in[i]; break;
      case 256:     bout= (const float*)d_in[i]; break;
      case 16384:   if (nw < 2) w16[nw++] = (const float*)d_in[i]; break;
      default: break;
    }
  }
  if (!in)   in  = (const float*)d_in[0];
  if (!cbp)  cbp = (const float*)d_in[1];
  if (nw < 2) { w16[0] = (const float*)d_in[2]; w16[1] = (const float*)d_in[4]; }
  if (!bin)  bin = (const float*)d_in[3];
  if (!bout) bout = (const float*)d_in[5];
  if (!rnd)  rnd = (const float*)d_in[6];

  u16* wsu = (u16*)d_ws;
  nsvq_prep<<<64, 256, 0, stream>>>(cbp, w16[0], w16[1], wsu);
  nsvq_main<<<1024, 128, 0, stream>>>(in, rnd, bin, bout, wsu, (float*)d_out);
}

// Round 7
// 124.091 us; speedup vs baseline: 1.0681x; 1.0681x over previous
//
#include <hip/hip_runtime.h>
#include <hip/hip_bf16.h>

typedef __bf16 bf16x8 __attribute__((ext_vector_type(8)));
typedef unsigned short u16x8 __attribute__((ext_vector_type(8)));
typedef unsigned int u32x2 __attribute__((ext_vector_type(2)));
typedef float f32x4 __attribute__((ext_vector_type(4)));
typedef unsigned short u16;

constexpr int DIMc = 256, Tt = 2048, Dd = 64;

// ws layout (u16 units):
//   CbF[1024][64] @0     : bf16(-2*c), fragment-row order (code-major) = 128 KB
//   CN[1024] f32  @65536 : ||c||^2 (exact partial-sum tree)            =   4 KB
//   WinT image    @67584 : [64][256] bf16, XOR-swizzled LDS image      =  32 KB
//   WoX  image    @83968 : [256][64] bf16, XOR-swizzled LDS image      =  32 KB
#define CBF_U  0
#define CN_U   65536
#define WINT_U 67584
#define WOX_U  83968

__device__ __forceinline__ u16 f2b(float f) {   // RNE float->bf16 bits
  unsigned u = __float_as_uint(f);
  return (u16)((u + 0x7FFFu + ((u >> 16) & 1u)) >> 16);
}
__device__ __forceinline__ unsigned f2b2(float a, float b) {  // packed RNE pair (low=a)
  return (unsigned)f2b(a) | ((unsigned)f2b(b) << 16);
}
__device__ __forceinline__ f32x4 mfma16(u16x8 a, u16x8 b, f32x4 c) {
  return __builtin_amdgcn_mfma_f32_16x16x32_bf16(
      __builtin_bit_cast(bf16x8, a), __builtin_bit_cast(bf16x8, b), c, 0, 0, 0);
}
// async 16B/lane global->LDS DMA; LDS dst = uniform base + lane*16 (HW rule)
__device__ __forceinline__ void dma16(const u16* g, u16* l) {
  __builtin_amdgcn_global_load_lds(
      (const __attribute__((address_space(1))) unsigned int*)g,
      (__attribute__((address_space(3))) unsigned int*)l, 16, 0, 0);
}

// Prep: all fp32->bf16 weight conversion + transposition done ONCE.
__global__ void nsvq_prep(const float* __restrict__ cb, const float* __restrict__ Win,
                          const float* __restrict__ Wout, u16* __restrict__ wsu) {
  const int g = blockIdx.x * 256 + threadIdx.x;   // 64 blocks -> 16384 threads
  {  // CbF: 4 values/thread, value = bf16(-2c); row k is MFMA-A fragment-ready
    const int k = g >> 4, j = (g & 15) << 2;
    float4 v = *(const float4*)(cb + k * 64 + j);
    u16* row = wsu + CBF_U + k * 64 + j;
    row[0] = f2b(-2.f * v.x); row[1] = f2b(-2.f * v.y);
    row[2] = f2b(-2.f * v.z); row[3] = f2b(-2.f * v.w);
  }
  if (g < 1024) {  // CN: exact partial-sum tree (bit-stable across rounds)
    const float* cr = cb + g * 64;
    float p[4];
    #pragma unroll
    for (int q = 0; q < 4; ++q) {
      float4 a0 = ((const float4*)(cr + q * 8))[0],      a1 = ((const float4*)(cr + q * 8))[1];
      float4 a2 = ((const float4*)(cr + 32 + q * 8))[0], a3 = ((const float4*)(cr + 32 + q * 8))[1];
      float pA = fmaf(a0.w, a0.w, fmaf(a0.z, a0.z, fmaf(a0.y, a0.y, a0.x * a0.x)));
      float pB = fmaf(a1.w, a1.w, fmaf(a1.z, a1.z, fmaf(a1.y, a1.y, a1.x * a1.x)));
      float pC = fmaf(a2.w, a2.w, fmaf(a2.z, a2.z, fmaf(a2.y, a2.y, a2.x * a2.x)));
      float pD = fmaf(a3.w, a3.w, fmaf(a3.z, a3.z, fmaf(a3.y, a3.y, a3.x * a3.x)));
      p[q] = (pA + pB) + (pC + pD);
    }
    ((float*)(wsu + CN_U))[g] = (p[0] + p[1]) + (p[2] + p[3]);
  }
  {  // WinT image: [d][c] swizzled (exact LDS image for DMA)
    const int d = g >> 8, c = g & 255;
    wsu[WINT_U + d * 256 + (((c >> 3) ^ (d & 7)) << 3) + (c & 7)] = f2b(Win[c * 64 + d]);
  }
  {  // WoX image: [c][d] swizzled (exact LDS image for DMA)
    const int c = g >> 6, d = g & 63;
    wsu[WOX_U + c * 64 + (((d >> 3) ^ (c & 7)) << 3) + (d & 7)] = f2b(Wout[d * 256 + c]);
  }
}

// Main: block = 32 tokens, 256 threads (4 waves), grid 1024 -> 4 blocks/CU,
// 16 waves/CU (50% occ). Wave w: th=w>>1 (token half), mh=w&1 (dim half).
// Encode: wave computes m-tiles {2mh,2mh+1} for tokens th*16..+16 (16 MFMA).
// Distance: wave-private 256-code slice x all 32 tokens (64 MFMA).
// Decode: c-tiles mh*8..+8 for tokens th*16..+16 (16 MFMA).
// LDS (u16): WinT[64][256] swz @0 (WoX[256][64] swz aliases after encode);
// Xt[32][64] swz @16384; f32 scratch @18432: mnp[4][32], xp[2][32], rp[2][32].
// Total 37,888 B -> 4 blocks/CU (151.5 KB). 4 barriers.
__global__ __launch_bounds__(256, 4) void nsvq_main(
    const float* __restrict__ in, const float* __restrict__ rnd,
    const float* __restrict__ bin, const float* __restrict__ bout,
    const u16* __restrict__ wsu, float* __restrict__ out) {
  __shared__ u16 sm[18944];
  u16* const WinT = sm;                    // [64][256] bf16 swz (encode A)
  u16* const WoX  = sm;                    // [256][64] bf16 swz (decode A, aliased)
  u16* const Xt   = sm + 16384;            // [32][64] bf16 x (later q), swz
  float* const fz = (float*)(sm + 18432);  // [0..127]=mnp [128..191]=xp [192..255]=rp

  const int tid  = threadIdx.x;
  const int lane = tid & 63;
  const int w    = tid >> 6;               // 0..3
  const int th   = w >> 1, mh = w & 1;
  const int quad = lane >> 4, col = lane & 15;
  const int b    = blockIdx.x >> 6;        // 16 batches x 64 token-tiles
  const int t0   = (blockIdx.x & 63) << 5;
  const int myt  = th * 16 + col;          // own token row in block (0..31)

  // ---- WinT DMA (32 KB = 32 instrs, 8 per wave), fully async ----
  #pragma unroll
  for (int ii = 0; ii < 8; ++ii) {
    const int i = w + 4 * ii;
    dma16(wsu + WINT_U + i * 512 + lane * 8, WinT + i * 512);
  }
  // ---- encode B-fragments straight from global (own 16 tokens, full K) ----
  u16x8 Bf[8];
  const float* ibase = in + (size_t)b * DIMc * Tt + t0 + myt;
  #pragma unroll
  for (int kt = 0; kt < 8; ++kt) {
    float v[8];
    #pragma unroll
    for (int j = 0; j < 8; ++j) v[j] = ibase[(size_t)(kt * 32 + quad * 8 + j) * Tt];
    u16x8 pk;
    #pragma unroll
    for (int j = 0; j < 8; ++j) pk[j] = f2b(v[j]);
    Bf[kt] = pk;
  }
  // ---- rnd (own tokens, own 32 dims, acc layout); partial rr2 -> LDS ----
  const float* rbase = rnd + ((size_t)b * Tt + t0 + myt) * Dd + mh * 32 + quad * 4;
  float4 rq0 = *(const float4*)(rbase);
  float4 rq1 = *(const float4*)(rbase + 16);
  float rr2p = 0.f;
  rr2p = fmaf(rq0.x, rq0.x, rr2p); rr2p = fmaf(rq0.y, rq0.y, rr2p);
  rr2p = fmaf(rq0.z, rq0.z, rr2p); rr2p = fmaf(rq0.w, rq0.w, rr2p);
  rr2p = fmaf(rq1.x, rq1.x, rr2p); rr2p = fmaf(rq1.y, rq1.y, rr2p);
  rr2p = fmaf(rq1.z, rq1.z, rr2p); rr2p = fmaf(rq1.w, rq1.w, rr2p);
  rr2p += __shfl_xor(rr2p, 16);
  rr2p += __shfl_xor(rr2p, 32);            // partial over dims [mh*32, mh*32+32)
  if (quad == 0) fz[192 + mh * 32 + myt] = rr2p;
  __syncthreads();   // B1: WinT ready

  // ---- encode: own 2 m-tiles, acc init = bin (f32-exact bias) ----
  f32x4 acc[2];
  #pragma unroll
  for (int mi = 0; mi < 2; ++mi) {
    const int mt = mh * 2 + mi;
    float4 bi = *(const float4*)(bin + mt * 16 + quad * 4);
    f32x4 a = {bi.x, bi.y, bi.z, bi.w};
    const int d = mt * 16 + col;
    #pragma unroll
    for (int kt = 0; kt < 8; ++kt) {
      u16x8 A = *(const u16x8*)(WinT + d * 256 + (((kt * 4 + quad) ^ (d & 7)) << 3));
      a = mfma16(A, Bf[kt], a);
    }
    acc[mi] = a;
  }
  float x2p = 0.f;
  #pragma unroll
  for (int mi = 0; mi < 2; ++mi) {
    const int mt = mh * 2 + mi;
    #pragma unroll
    for (int r = 0; r < 4; ++r) x2p = fmaf(acc[mi][r], acc[mi][r], x2p);
    u32x2 px = { f2b2(acc[mi][0], acc[mi][1]), f2b2(acc[mi][2], acc[mi][3]) };
    const int bk  = mt * 2 + (quad >> 1);
    const int off = myt * 64 + ((bk ^ (myt & 7)) << 3) + (quad & 1) * 4;
    *(u32x2*)(Xt + off) = px;
  }
  x2p += __shfl_xor(x2p, 16);
  x2p += __shfl_xor(x2p, 32);              // partial ||x||^2 over own 32 dims
  if (quad == 0) fz[128 + mh * 32 + myt] = x2p;
  __syncthreads();   // B2: Xt(x) full (both dim-halves), xp written

  // ---- WoX DMA (aliases WinT, now dead; drains by B3) ----
  #pragma unroll
  for (int ii = 0; ii < 8; ++ii) {
    const int i = w + 4 * ii;
    dma16(wsu + WOX_U + i * 512 + lane * 8, WoX + i * 512);
  }
  // ---- distances: wave-private 256-code slice over all 32 tokens ----
  u16x8 Xa[2], Xb[2];
  #pragma unroll
  for (int nt = 0; nt < 2; ++nt) {
    const int tr = nt * 16 + col;
    Xa[nt] = *(const u16x8*)(Xt + tr * 64 + ((quad ^ (tr & 7)) << 3));
    Xb[nt] = *(const u16x8*)(Xt + tr * 64 + (((4 + quad) ^ (tr & 7)) << 3));
  }
  float minv[2] = {3.4e38f, 3.4e38f};
  const u16* cwf   = wsu + CBF_U + (size_t)(w * 256) * 64;
  const float* cnp = (const float*)(wsu + CN_U) + w * 256;
  #pragma unroll 4
  for (int mi = 0; mi < 16; ++mi) {
    u16x8 A0 = *(const u16x8*)(cwf + (mi * 16 + col) * 64 + quad * 8);
    u16x8 A1 = *(const u16x8*)(cwf + (mi * 16 + col) * 64 + 32 + quad * 8);
    f32x4 cn4 = *(const f32x4*)(cnp + mi * 16 + quad * 4);
    #pragma unroll
    for (int nt = 0; nt < 2; ++nt) {
      f32x4 a = mfma16(A0, Xa[nt], cn4);   // c^2 + x·(-2c)
      a = mfma16(A1, Xb[nt], a);
      #pragma unroll
      for (int r = 0; r < 4; ++r) minv[nt] = fminf(minv[nt], a[r]);
    }
  }
  #pragma unroll
  for (int nt = 0; nt < 2; ++nt) {
    float m = minv[nt];
    m = fminf(m, __shfl_xor(m, 16));
    m = fminf(m, __shfl_xor(m, 32));
    if (quad == 0) fz[w * 32 + nt * 16 + col] = m;
  }
  __syncthreads();   // B3: mnp ready; xp/rp visible; WoX DMA drained

  // ---- q = x + sc*rnd in registers (own tokens, own dim-half) ----
  float mv = fminf(fminf(fz[myt], fz[32 + myt]), fminf(fz[64 + myt], fz[96 + myt]));
  float x2v  = fz[128 + myt] + fz[160 + myt];
  float rr2v = fz[192 + myt] + fz[224 + myt];
  float r2  = fmaxf(x2v + mv, 0.f);                 // ||x - hard||^2
  float scv = sqrtf(r2) / (sqrtf(rr2v) + 1e-12f);   // own token's scale
  #pragma unroll
  for (int mi = 0; mi < 2; ++mi) {
    const int mt = mh * 2 + mi;
    float4 r = mi ? rq1 : rq0;
    float q0 = fmaf(scv, r.x, acc[mi][0]);
    float q1 = fmaf(scv, r.y, acc[mi][1]);
    float q2 = fmaf(scv, r.z, acc[mi][2]);
    float q3 = fmaf(scv, r.w, acc[mi][3]);
    u32x2 pq = { f2b2(q0, q1), f2b2(q2, q3) };
    const int bk  = mt * 2 + (quad >> 1);
    const int off = myt * 64 + ((bk ^ (myt & 7)) << 3) + (quad & 1) * 4;
    *(u32x2*)(Xt + off) = pq;
  }
  __syncthreads();   // B4: Xt(q) full (both dim-halves)

  // ---- decode: own 8 c-tiles for own 16 tokens, acc init = bout ----
  u16x8 Q0 = *(const u16x8*)(Xt + myt * 64 + ((quad ^ (myt & 7)) << 3));
  u16x8 Q1 = *(const u16x8*)(Xt + myt * 64 + (((4 + quad) ^ (myt & 7)) << 3));
  float* ob0 = out + (size_t)b * DIMc * Tt + t0 + myt;
  #pragma unroll
  for (int mi = 0; mi < 8; ++mi) {
    const int mt = mh * 8 + mi;
    const int c = mt * 16 + col;
    const u16* ar = WoX + c * 64;
    u16x8 A0 = *(const u16x8*)(ar + ((quad ^ (c & 7)) << 3));
    u16x8 A1 = *(const u16x8*)(ar + (((4 + quad) ^ (c & 7)) << 3));
    float4 bo = *(const float4*)(bout + mt * 16 + quad * 4);
    f32x4 a = {bo.x, bo.y, bo.z, bo.w};
    a = mfma16(A0, Q0, a);
    a = mfma16(A1, Q1, a);
    float* ob = ob0 + (size_t)(mt * 16 + quad * 4) * Tt;
    #pragma unroll
    for (int r = 0; r < 4; ++r) ob[(size_t)r * Tt] = a[r];
  }
}

extern "C" void kernel_launch(void* const* d_in, const int* in_sizes, int n_in,
                              void* d_out, int out_size, void* d_ws, size_t ws_size,
                              hipStream_t stream) {
  const float *in = nullptr, *cbp = nullptr, *rnd = nullptr, *bin = nullptr, *bout = nullptr;
  const float* w16[2] = {nullptr, nullptr}; int nw = 0;
  for (int i = 0; i < n_in; ++i) {
    switch (in_sizes[i]) {
      case 8388608: in  = (const float*)d_in[i]; break;
      case 65536:   cbp = (const float*)d_in[i]; break;
      case 2097152: rnd = (const float*)d_in[i]; break;
      case 64:      bin = (const float*)d_in[i]; break;
      case 256:     bout= (const float*)d_in[i]; break;
      case 16384:   if (nw < 2) w16[nw++] = (const float*)d_in[i]; break;
      default: break;
    }
  }
  if (!in)   in  = (const float*)d_in[0];
  if (!cbp)  cbp = (const float*)d_in[1];
  if (nw < 2) { w16[0] = (const float*)d_in[2]; w16[1] = (const float*)d_in[4]; }
  if (!bin)  bin = (const float*)d_in[3];
  if (!bout) bout = (const float*)d_in[5];
  if (!rnd)  rnd = (const float*)d_in[6];

  u16* wsu = (u16*)d_ws;
  nsvq_prep<<<64, 256, 0, stream>>>(cbp, w16[0], w16[1], wsu);
  nsvq_main<<<1024, 256, 0, stream>>>(in, rnd, bin, bout, wsu, (float*)d_out);
}

// Round 8
// 123.981 us; speedup vs baseline: 1.0691x; 1.0009x over previous
//
#include <hip/hip_runtime.h>
#include <hip/hip_bf16.h>

typedef __bf16 bf16x8 __attribute__((ext_vector_type(8)));
typedef unsigned short u16x8 __attribute__((ext_vector_type(8)));
typedef unsigned int u32x2 __attribute__((ext_vector_type(2)));
typedef float f32x4 __attribute__((ext_vector_type(4)));
typedef unsigned short u16;

constexpr int DIMc = 256, Tt = 2048, Dd = 64;

// ws layout (u16 units):
//   CbF[1024][64] @0     : bf16(-2*c), fragment-row order (code-major) = 128 KB
//   CN[1024] f32  @65536 : ||c||^2 (exact partial-sum tree)            =   4 KB
//   WinT image    @67584 : [64][256] bf16, XOR-swizzled LDS image      =  32 KB
//   WoX  image    @83968 : [256][64] bf16, XOR-swizzled LDS image      =  32 KB
#define CBF_U  0
#define CN_U   65536
#define WINT_U 67584
#define WOX_U  83968

__device__ __forceinline__ u16 f2b(float f) {   // RNE float->bf16 bits
  unsigned u = __float_as_uint(f);
  return (u16)((u + 0x7FFFu + ((u >> 16) & 1u)) >> 16);
}
__device__ __forceinline__ unsigned f2b2(float a, float b) {  // packed RNE pair (low=a)
  return (unsigned)f2b(a) | ((unsigned)f2b(b) << 16);
}
__device__ __forceinline__ f32x4 mfma16(u16x8 a, u16x8 b, f32x4 c) {
  return __builtin_amdgcn_mfma_f32_16x16x32_bf16(
      __builtin_bit_cast(bf16x8, a), __builtin_bit_cast(bf16x8, b), c, 0, 0, 0);
}
// async 16B/lane global->LDS DMA; LDS dst = uniform base + lane*16 (HW rule)
__device__ __forceinline__ void dma16(const u16* g, u16* l) {
  __builtin_amdgcn_global_load_lds(
      (const __attribute__((address_space(1))) unsigned int*)g,
      (__attribute__((address_space(3))) unsigned int*)l, 16, 0, 0);
}

// Prep: all fp32->bf16 weight conversion + transposition done ONCE.
__global__ void nsvq_prep(const float* __restrict__ cb, const float* __restrict__ Win,
                          const float* __restrict__ Wout, u16* __restrict__ wsu) {
  const int g = blockIdx.x * 256 + threadIdx.x;   // 64 blocks -> 16384 threads
  {  // CbF: 4 values/thread, value = bf16(-2c); row k is MFMA-A fragment-ready
    const int k = g >> 4, j = (g & 15) << 2;
    float4 v = *(const float4*)(cb + k * 64 + j);
    u16* row = wsu + CBF_U + k * 64 + j;
    row[0] = f2b(-2.f * v.x); row[1] = f2b(-2.f * v.y);
    row[2] = f2b(-2.f * v.z); row[3] = f2b(-2.f * v.w);
  }
  if (g < 1024) {  // CN: exact partial-sum tree (bit-stable across rounds)
    const float* cr = cb + g * 64;
    float p[4];
    #pragma unroll
    for (int q = 0; q < 4; ++q) {
      float4 a0 = ((const float4*)(cr + q * 8))[0],      a1 = ((const float4*)(cr + q * 8))[1];
      float4 a2 = ((const float4*)(cr + 32 + q * 8))[0], a3 = ((const float4*)(cr + 32 + q * 8))[1];
      float pA = fmaf(a0.w, a0.w, fmaf(a0.z, a0.z, fmaf(a0.y, a0.y, a0.x * a0.x)));
      float pB = fmaf(a1.w, a1.w, fmaf(a1.z, a1.z, fmaf(a1.y, a1.y, a1.x * a1.x)));
      float pC = fmaf(a2.w, a2.w, fmaf(a2.z, a2.z, fmaf(a2.y, a2.y, a2.x * a2.x)));
      float pD = fmaf(a3.w, a3.w, fmaf(a3.z, a3.z, fmaf(a3.y, a3.y, a3.x * a3.w == a3.w ? a3.w : a3.w)));
      // (identical arithmetic to prior rounds)
      pD = fmaf(a3.w, a3.w, fmaf(a3.z, a3.z, fmaf(a3.y, a3.y, a3.x * a3.x)));
      p[q] = (pA + pB) + (pC + pD);
    }
    ((float*)(wsu + CN_U))[g] = (p[0] + p[1]) + (p[2] + p[3]);
  }
  {  // WinT image: [d][c] swizzled (exact LDS image for DMA)
    const int d = g >> 8, c = g & 255;
    wsu[WINT_U + d * 256 + (((c >> 3) ^ (d & 7)) << 3) + (c & 7)] = f2b(Win[c * 64 + d]);
  }
  {  // WoX image: [c][d] swizzled (exact LDS image for DMA)
    const int c = g >> 6, d = g & 63;
    wsu[WOX_U + c * 64 + (((d >> 3) ^ (c & 7)) << 3) + (d & 7)] = f2b(Wout[d * 256 + c]);
  }
}

// Main: block = 64 tokens, 512 threads (8 waves), grid 512 -> 2 blocks/CU,
// 16 waves/CU (50% occ) at round-5 per-block weight traffic.
// Wave w: th=w>>1 (16-token group), mh=w&1 (32-dim half).
// Encode: m-tiles {2mh,2mh+1} x own tokens (16 MFMA). Distance: own 128-code
// slice x all 64 tokens (64 MFMA). Decode: c-tiles mh*8..+8 x own tokens (16).
// LDS (u16): WinT[64][256] swz @0 ; WoX[256][64] swz @16384 ; Xt[64][64] swz
// @32768 ; f32 fz @36864: mnp[8][64], xp[2][64], rp[2][64]. Total 76,800 B.
__global__ __launch_bounds__(512, 4) void nsvq_main(
    const float* __restrict__ in, const float* __restrict__ rnd,
    const float* __restrict__ bin, const float* __restrict__ bout,
    const u16* __restrict__ wsu, float* __restrict__ out) {
  __shared__ u16 sm[38400];
  u16* const WinT = sm;                    // [64][256] bf16 swz (encode A)
  u16* const WoX  = sm + 16384;            // [256][64] bf16 swz (decode A)
  u16* const Xt   = sm + 32768;            // [64][64] bf16 x (later q), swz
  float* const fz = (float*)(sm + 36864);  // [0..511]=mnp [512..639]=xp [640..767]=rp

  const int tid  = threadIdx.x;
  const int lane = tid & 63;
  const int w    = tid >> 6;               // 0..7
  const int th   = w >> 1, mh = w & 1;
  const int quad = lane >> 4, col = lane & 15;
  const int b    = blockIdx.x >> 5;        // 16 batches x 32 token-tiles
  const int t0   = (blockIdx.x & 31) << 6;
  const int myt  = th * 16 + col;          // own token row in block (0..63)

  // ---- WinT + WoX DMA (64 KB = 64 instrs, 8 per wave), fully async ----
  #pragma unroll
  for (int ii = 0; ii < 4; ++ii) {
    const int i = w + 8 * ii;
    dma16(wsu + WINT_U + i * 512 + lane * 8, WinT + i * 512);
  }
  #pragma unroll
  for (int ii = 0; ii < 4; ++ii) {
    const int i = w + 8 * ii;
    dma16(wsu + WOX_U + i * 512 + lane * 8, WoX + i * 512);
  }
  // ---- encode B-fragments straight from global (own 16 tokens, full K) ----
  u16x8 Bf[8];
  const float* ibase = in + (size_t)b * DIMc * Tt + t0 + myt;
  #pragma unroll
  for (int kt = 0; kt < 8; ++kt) {
    float v[8];
    #pragma unroll
    for (int j = 0; j < 8; ++j) v[j] = ibase[(size_t)(kt * 32 + quad * 8 + j) * Tt];
    u16x8 pk;
    #pragma unroll
    for (int j = 0; j < 8; ++j) pk[j] = f2b(v[j]);
    Bf[kt] = pk;
  }
  // ---- rnd (own tokens, own 32 dims, acc layout); partial rr2 -> LDS ----
  const float* rbase = rnd + ((size_t)b * Tt + t0 + myt) * Dd + mh * 32 + quad * 4;
  float4 rq0 = *(const float4*)(rbase);
  float4 rq1 = *(const float4*)(rbase + 16);
  float rr2p = 0.f;
  rr2p = fmaf(rq0.x, rq0.x, rr2p); rr2p = fmaf(rq0.y, rq0.y, rr2p);
  rr2p = fmaf(rq0.z, rq0.z, rr2p); rr2p = fmaf(rq0.w, rq0.w, rr2p);
  rr2p = fmaf(rq1.x, rq1.x, rr2p); rr2p = fmaf(rq1.y, rq1.y, rr2p);
  rr2p = fmaf(rq1.z, rq1.z, rr2p); rr2p = fmaf(rq1.w, rq1.w, rr2p);
  rr2p += __shfl_xor(rr2p, 16);
  rr2p += __shfl_xor(rr2p, 32);            // partial over dims [mh*32, mh*32+32)
  if (quad == 0) fz[640 + mh * 64 + myt] = rr2p;
  __syncthreads();   // B1: WinT + WoX ready

  // ---- encode: own 2 m-tiles, acc init = bin (f32-exact bias) ----
  f32x4 acc[2];
  #pragma unroll
  for (int mi = 0; mi < 2; ++mi) {
    const int mt = mh * 2 + mi;
    float4 bi = *(const float4*)(bin + mt * 16 + quad * 4);
    f32x4 a = {bi.x, bi.y, bi.z, bi.w};
    const int d = mt * 16 + col;
    #pragma unroll
    for (int kt = 0; kt < 8; ++kt) {
      u16x8 A = *(const u16x8*)(WinT + d * 256 + (((kt * 4 + quad) ^ (d & 7)) << 3));
      a = mfma16(A, Bf[kt], a);
    }
    acc[mi] = a;
  }
  float x2p = 0.f;
  #pragma unroll
  for (int mi = 0; mi < 2; ++mi) {
    const int mt = mh * 2 + mi;
    #pragma unroll
    for (int r = 0; r < 4; ++r) x2p = fmaf(acc[mi][r], acc[mi][r], x2p);
    u32x2 px = { f2b2(acc[mi][0], acc[mi][1]), f2b2(acc[mi][2], acc[mi][3]) };
    const int bk  = mt * 2 + (quad >> 1);
    const int off = myt * 64 + ((bk ^ (myt & 7)) << 3) + (quad & 1) * 4;
    *(u32x2*)(Xt + off) = px;
  }
  x2p += __shfl_xor(x2p, 16);
  x2p += __shfl_xor(x2p, 32);              // partial ||x||^2 over own 32 dims
  if (quad == 0) fz[512 + mh * 64 + myt] = x2p;
  __syncthreads();   // B2: Xt(x) full, xp written

  // ---- distances: own 128-code slice over all 64 tokens ----
  u16x8 Xa[4], Xb[4];
  #pragma unroll
  for (int nt = 0; nt < 4; ++nt) {
    const int tr = nt * 16 + col;
    Xa[nt] = *(const u16x8*)(Xt + tr * 64 + ((quad ^ (tr & 7)) << 3));
    Xb[nt] = *(const u16x8*)(Xt + tr * 64 + (((4 + quad) ^ (tr & 7)) << 3));
  }
  float minv[4];
  #pragma unroll
  for (int i = 0; i < 4; ++i) minv[i] = 3.4e38f;
  const u16* cwf   = wsu + CBF_U + (size_t)(w * 128) * 64;
  const float* cnp = (const float*)(wsu + CN_U) + w * 128;
  #pragma unroll
  for (int mi = 0; mi < 8; ++mi) {
    u16x8 A0 = *(const u16x8*)(cwf + (mi * 16 + col) * 64 + quad * 8);
    u16x8 A1 = *(const u16x8*)(cwf + (mi * 16 + col) * 64 + 32 + quad * 8);
    f32x4 cn4 = *(const f32x4*)(cnp + mi * 16 + quad * 4);
    #pragma unroll
    for (int nt = 0; nt < 4; ++nt) {
      f32x4 a = mfma16(A0, Xa[nt], cn4);   // c^2 + x·(-2c)
      a = mfma16(A1, Xb[nt], a);
      #pragma unroll
      for (int r = 0; r < 4; ++r) minv[nt] = fminf(minv[nt], a[r]);
    }
  }
  #pragma unroll
  for (int nt = 0; nt < 4; ++nt) {
    float m = minv[nt];
    m = fminf(m, __shfl_xor(m, 16));
    m = fminf(m, __shfl_xor(m, 32));
    if (quad == 0) fz[w * 64 + nt * 16 + col] = m;
  }
  __syncthreads();   // B3: mnp ready; xp/rp visible

  // ---- q = x + sc*rnd in registers (own tokens, own dim-half) ----
  float mv = 3.4e38f;
  #pragma unroll
  for (int j = 0; j < 8; ++j) mv = fminf(mv, fz[j * 64 + myt]);
  float x2v  = fz[512 + myt] + fz[576 + myt];
  float rr2v = fz[640 + myt] + fz[704 + myt];
  float r2  = fmaxf(x2v + mv, 0.f);                 // ||x - hard||^2
  float scv = sqrtf(r2) / (sqrtf(rr2v) + 1e-12f);   // own token's scale
  #pragma unroll
  for (int mi = 0; mi < 2; ++mi) {
    const int mt = mh * 2 + mi;
    float4 r = mi ? rq1 : rq0;
    float q0 = fmaf(scv, r.x, acc[mi][0]);
    float q1 = fmaf(scv, r.y, acc[mi][1]);
    float q2 = fmaf(scv, r.z, acc[mi][2]);
    float q3 = fmaf(scv, r.w, acc[mi][3]);
    u32x2 pq = { f2b2(q0, q1), f2b2(q2, q3) };
    const int bk  = mt * 2 + (quad >> 1);
    const int off = myt * 64 + ((bk ^ (myt & 7)) << 3) + (quad & 1) * 4;
    *(u32x2*)(Xt + off) = pq;
  }
  __syncthreads();   // B4: Xt(q) full (both dim-halves)

  // ---- decode: own 8 c-tiles for own 16 tokens, acc init = bout ----
  u16x8 Q0 = *(const u16x8*)(Xt + myt * 64 + ((quad ^ (myt & 7)) << 3));
  u16x8 Q1 = *(const u16x8*)(Xt + myt * 64 + (((4 + quad) ^ (myt & 7)) << 3));
  float* ob0 = out + (size_t)b * DIMc * Tt + t0 + myt;
  #pragma unroll
  for (int mi = 0; mi < 8; ++mi) {
    const int mt = mh * 8 + mi;
    const int c = mt * 16 + col;
    const u16* ar = WoX + c * 64;
    u16x8 A0 = *(const u16x8*)(ar + ((quad ^ (c & 7)) << 3));
    u16x8 A1 = *(const u16x8*)(ar + (((4 + quad) ^ (c & 7)) << 3));
    float4 bo = *(const float4*)(bout + mt * 16 + quad * 4);
    f32x4 a = {bo.x, bo.y, bo.z, bo.w};
    a = mfma16(A0, Q0, a);
    a = mfma16(A1, Q1, a);
    float* ob = ob0 + (size_t)(mt * 16 + quad * 4) * Tt;
    #pragma unroll
    for (int r = 0; r < 4; ++r) ob[(size_t)r * Tt] = a[r];
  }
}

extern "C" void kernel_launch(void* const* d_in, const int* in_sizes, int n_in,
                              void* d_out, int out_size, void* d_ws, size_t ws_size,
                              hipStream_t stream) {
  const float *in = nullptr, *cbp = nullptr, *rnd = nullptr, *bin = nullptr, *bout = nullptr;
  const float* w16[2] = {nullptr, nullptr}; int nw = 0;
  for (int i = 0; i < n_in; ++i) {
    switch (in_sizes[i]) {
      case 8388608: in  = (const float*)d_in[i]; break;
      case 65536:   cbp = (const float*)d_in[i]; break;
      case 2097152: rnd = (const float*)d_in[i]; break;
      case 64:      bin = (const float*)d_in[i]; break;
      case 256:     bout= (const float*)d_in[i]; break;
      case 16384:   if (nw < 2) w16[nw++] = (const float*)d_in[i]; break;
      default: break;
    }
  }
  if (!in)   in  = (const float*)d_in[0];
  if (!cbp)  cbp = (const float*)d_in[1];
  if (nw < 2) { w16[0] = (const float*)d_in[2]; w16[1] = (const float*)d_in[4]; }
  if (!bin)  bin = (const float*)d_in[3];
  if (!bout) bout = (const float*)d_in[5];
  if (!rnd)  rnd = (const float*)d_in[6];

  u16* wsu = (u16*)d_ws;
  nsvq_prep<<<64, 256, 0, stream>>>(cbp, w16[0], w16[1], wsu);
  nsvq_main<<<512, 512, 0, stream>>>(in, rnd, bin, bout, wsu, (float*)d_out);
}

// Round 9
// 112.595 us; speedup vs baseline: 1.1772x; 1.1011x over previous
//
#include <hip/hip_runtime.h>
#include <hip/hip_bf16.h>

typedef __bf16 bf16x8 __attribute__((ext_vector_type(8)));
typedef unsigned short u16x8 __attribute__((ext_vector_type(8)));
typedef unsigned int u32x2 __attribute__((ext_vector_type(2)));
typedef float f32x4 __attribute__((ext_vector_type(4)));
typedef unsigned short u16;

constexpr int DIMc = 256, Tt = 2048, Dd = 64;

// ws layout (u16 units):
//   CbF[1024][64] @0     : bf16(-2*c), fragment-row order (code-major) = 128 KB
//   CN[1024] f32  @65536 : ||c||^2 (exact partial-sum tree)            =   4 KB
//   WinT image    @67584 : [64][256] bf16, XOR-swizzled LDS image      =  32 KB
//   WoX  image    @83968 : [256][64] bf16, XOR-swizzled LDS image      =  32 KB
#define CBF_U  0
#define CN_U   65536
#define WINT_U 67584
#define WOX_U  83968

__device__ __forceinline__ u16 f2b(float f) {   // RNE float->bf16 bits
  unsigned u = __float_as_uint(f);
  return (u16)((u + 0x7FFFu + ((u >> 16) & 1u)) >> 16);
}
__device__ __forceinline__ unsigned f2b2(float a, float b) {  // packed RNE pair (low=a)
  return (unsigned)f2b(a) | ((unsigned)f2b(b) << 16);
}
__device__ __forceinline__ f32x4 mfma16(u16x8 a, u16x8 b, f32x4 c) {
  return __builtin_amdgcn_mfma_f32_16x16x32_bf16(
      __builtin_bit_cast(bf16x8, a), __builtin_bit_cast(bf16x8, b), c, 0, 0, 0);
}
// async 16B/lane global->LDS DMA; LDS dst = uniform base + lane*16 (HW rule)
__device__ __forceinline__ void dma16(const u16* g, u16* l) {
  __builtin_amdgcn_global_load_lds(
      (const __attribute__((address_space(1))) unsigned int*)g,
      (__attribute__((address_space(3))) unsigned int*)l, 16, 0, 0);
}

// Prep: all fp32->bf16 weight conversion + transposition done ONCE.
__global__ void nsvq_prep(const float* __restrict__ cb, const float* __restrict__ Win,
                          const float* __restrict__ Wout, u16* __restrict__ wsu) {
  const int g = blockIdx.x * 256 + threadIdx.x;   // 64 blocks -> 16384 threads
  {  // CbF: 4 values/thread, value = bf16(-2c); row k is MFMA-A fragment-ready
    const int k = g >> 4, j = (g & 15) << 2;
    float4 v = *(const float4*)(cb + k * 64 + j);
    u16* row = wsu + CBF_U + k * 64 + j;
    row[0] = f2b(-2.f * v.x); row[1] = f2b(-2.f * v.y);
    row[2] = f2b(-2.f * v.z); row[3] = f2b(-2.f * v.w);
  }
  if (g < 1024) {  // CN: exact partial-sum tree (bit-stable across rounds)
    const float* cr = cb + g * 64;
    float p[4];
    #pragma unroll
    for (int q = 0; q < 4; ++q) {
      float4 a0 = ((const float4*)(cr + q * 8))[0],      a1 = ((const float4*)(cr + q * 8))[1];
      float4 a2 = ((const float4*)(cr + 32 + q * 8))[0], a3 = ((const float4*)(cr + 32 + q * 8))[1];
      float pA = fmaf(a0.w, a0.w, fmaf(a0.z, a0.z, fmaf(a0.y, a0.y, a0.x * a0.x)));
      float pB = fmaf(a1.w, a1.w, fmaf(a1.z, a1.z, fmaf(a1.y, a1.y, a1.x * a1.x)));
      float pC = fmaf(a2.w, a2.w, fmaf(a2.z, a2.z, fmaf(a2.y, a2.y, a2.x * a2.x)));
      float pD = fmaf(a3.w, a3.w, fmaf(a3.z, a3.z, fmaf(a3.y, a3.y, a3.x * a3.x)));
      p[q] = (pA + pB) + (pC + pD);
    }
    ((float*)(wsu + CN_U))[g] = (p[0] + p[1]) + (p[2] + p[3]);
  }
  {  // WinT image: [d][c] swizzled (exact LDS image for DMA)
    const int d = g >> 8, c = g & 255;
    wsu[WINT_U + d * 256 + (((c >> 3) ^ (d & 7)) << 3) + (c & 7)] = f2b(Win[c * 64 + d]);
  }
  {  // WoX image: [c][d] swizzled (exact LDS image for DMA)
    const int c = g >> 6, d = g & 63;
    wsu[WOX_U + c * 64 + (((d >> 3) ^ (c & 7)) << 3) + (d & 7)] = f2b(Wout[d * 256 + c]);
  }
}

// Main: block = 64 tokens, 256 threads (4 waves), grid 512 (2 blocks/CU).
// LDS (u16): WinT[64][256] swz @0 ; WoX[256][64] swz @16384 ; Xt[64][64] swz
// @32768 ; mnp[4][64]f @36864. Total 74,752 B -> 2 blocks/CU. 3 barriers.
__global__ __launch_bounds__(256, 2) void nsvq_main(
    const float* __restrict__ in, const float* __restrict__ rnd,
    const float* __restrict__ bin, const float* __restrict__ bout,
    const u16* __restrict__ wsu, float* __restrict__ out) {
  __shared__ u16 sm[37376];
  u16* const WinT = sm;                     // [64][256] bf16 swz (encode A)
  u16* const WoX  = sm + 16384;             // [256][64] bf16 swz (decode A)
  u16* const Xt   = sm + 32768;             // [64][64] bf16 x (later q), swz
  float* const mnp = (float*)(sm + 36864);  // [4][64] per-wave code-slice mins

  const int tid  = threadIdx.x;
  const int lane = tid & 63;
  const int w    = tid >> 6;                // 0..3
  const int quad = lane >> 4, col = lane & 15;
  const int b    = blockIdx.x >> 5;         // 16 batches x 32 token-tiles
  const int t0   = (blockIdx.x & 31) << 6;
  const int myt  = w * 16 + col;            // own token row in block (0..63)

  // ---- WinT + WoX DMA (64 KB = 64 instrs, 16 per wave), fully async ----
  #pragma unroll
  for (int ii = 0; ii < 8; ++ii) {
    const int i = w + 4 * ii;
    dma16(wsu + WINT_U + i * 512 + lane * 8, WinT + i * 512);
  }
  #pragma unroll
  for (int ii = 0; ii < 8; ++ii) {
    const int i = w + 4 * ii;
    dma16(wsu + WOX_U + i * 512 + lane * 8, WoX + i * 512);
  }
  // ---- encode B-fragments straight from global (own token only; 64B-granule) ----
  u16x8 Bf[8];
  const float* ibase = in + (size_t)b * DIMc * Tt + t0 + myt;
  #pragma unroll
  for (int kt = 0; kt < 8; ++kt) {
    float v[8];
    #pragma unroll
    for (int j = 0; j < 8; ++j) v[j] = ibase[(size_t)(kt * 32 + quad * 8 + j) * Tt];
    u16x8 pk;
    #pragma unroll
    for (int j = 0; j < 8; ++j) pk[j] = f2b(v[j]);
    Bf[kt] = pk;
  }
  // ---- rnd in acc-fragment layout (token=col, d=mt*16+quad*4+r); rr2 reduce ----
  float4 rq[4];
  {
    const float* rbase = rnd + ((size_t)b * Tt + t0 + myt) * Dd + quad * 4;
    #pragma unroll
    for (int mt = 0; mt < 4; ++mt) rq[mt] = *(const float4*)(rbase + mt * 16);
  }
  float rr2v = 0.f;
  #pragma unroll
  for (int mt = 0; mt < 4; ++mt) {
    rr2v = fmaf(rq[mt].x, rq[mt].x, rr2v); rr2v = fmaf(rq[mt].y, rq[mt].y, rr2v);
    rr2v = fmaf(rq[mt].z, rq[mt].z, rr2v); rr2v = fmaf(rq[mt].w, rq[mt].w, rr2v);
  }
  rr2v += __shfl_xor(rr2v, 16);
  rr2v += __shfl_xor(rr2v, 32);             // full ||rnd||^2, replicated over quads
  __syncthreads();   // WinT + WoX DMA drained

  // ---- encode: X^T = WinT · In, acc init = bin (f32-exact bias) ----
  f32x4 acc[4];
  #pragma unroll
  for (int mt = 0; mt < 4; ++mt) {
    float4 bi = *(const float4*)(bin + mt * 16 + quad * 4);
    f32x4 a = {bi.x, bi.y, bi.z, bi.w};
    const int d = mt * 16 + col;
    #pragma unroll
    for (int kt = 0; kt < 8; ++kt) {
      u16x8 A = *(const u16x8*)(WinT + d * 256 + (((kt * 4 + quad) ^ (d & 7)) << 3));
      a = mfma16(A, Bf[kt], a);
    }
    acc[mt] = a;
  }
  float x2v = 0.f;
  #pragma unroll
  for (int mt = 0; mt < 4; ++mt) {
    #pragma unroll
    for (int r = 0; r < 4; ++r) x2v = fmaf(acc[mt][r], acc[mt][r], x2v);
    u32x2 px = { f2b2(acc[mt][0], acc[mt][1]), f2b2(acc[mt][2], acc[mt][3]) };
    const int bk  = mt * 2 + (quad >> 1);
    const int off = myt * 64 + ((bk ^ (myt & 7)) << 3) + (quad & 1) * 4;
    *(u32x2*)(Xt + off) = px;
  }
  x2v += __shfl_xor(x2v, 16);
  x2v += __shfl_xor(x2v, 32);
  __syncthreads();   // Xt(x) ready for cross-wave reads

  // ---- distances: wave-private 256-code slice; fragment-ready CbF from L2 ----
  u16x8 Xa[4], Xb[4];
  #pragma unroll
  for (int nt = 0; nt < 4; ++nt) {
    const int tr = nt * 16 + col;
    Xa[nt] = *(const u16x8*)(Xt + tr * 64 + ((quad ^ (tr & 7)) << 3));
    Xb[nt] = *(const u16x8*)(Xt + tr * 64 + (((4 + quad) ^ (tr & 7)) << 3));
  }
  float minv[4];
  #pragma unroll
  for (int i = 0; i < 4; ++i) minv[i] = 3.4e38f;
  const u16* cwf   = wsu + CBF_U + (size_t)(w * 256) * 64;
  const float* cnp = (const float*)(wsu + CN_U) + w * 256;
  #pragma unroll 4
  for (int mi = 0; mi < 16; ++mi) {
    u16x8 A0 = *(const u16x8*)(cwf + (mi * 16 + col) * 64 + quad * 8);
    u16x8 A1 = *(const u16x8*)(cwf + (mi * 16 + col) * 64 + 32 + quad * 8);
    f32x4 cn4 = *(const f32x4*)(cnp + mi * 16 + quad * 4);
    #pragma unroll
    for (int nt = 0; nt < 4; ++nt) {
      f32x4 a = mfma16(A0, Xa[nt], cn4);    // c^2 + x·(-2c)
      a = mfma16(A1, Xb[nt], a);
      #pragma unroll
      for (int r = 0; r < 4; ++r) minv[nt] = fminf(minv[nt], a[r]);
    }
  }
  #pragma unroll
  for (int nt = 0; nt < 4; ++nt) {
    float m = minv[nt];
    m = fminf(m, __shfl_xor(m, 16));
    m = fminf(m, __shfl_xor(m, 32));
    mnp[w * 64 + nt * 16 + col] = m;        // all quads write same value
  }
  __syncthreads();   // mnp ready; all Xt(x) reads complete

  // ---- q = x + sc*rnd entirely in registers (acc layout); store q to Xt ----
  float mv = 3.4e38f;
  #pragma unroll
  for (int j = 0; j < 4; ++j) mv = fminf(mv, mnp[j * 64 + myt]);
  float r2  = fmaxf(x2v + mv, 0.f);                 // ||x - hard||^2
  float scv = sqrtf(r2) / (sqrtf(rr2v) + 1e-12f);   // own token's scale (per col)
  #pragma unroll
  for (int mt = 0; mt < 4; ++mt) {
    float q0 = fmaf(scv, rq[mt].x, acc[mt][0]);
    float q1 = fmaf(scv, rq[mt].y, acc[mt][1]);
    float q2 = fmaf(scv, rq[mt].z, acc[mt][2]);
    float q3 = fmaf(scv, rq[mt].w, acc[mt][3]);
    u32x2 pq = { f2b2(q0, q1), f2b2(q2, q3) };
    const int bk  = mt * 2 + (quad >> 1);
    const int off = myt * 64 + ((bk ^ (myt & 7)) << 3) + (quad & 1) * 4;
    *(u32x2*)(Xt + off) = pq;               // own row; same-wave LDS order suffices
  }

  // ---- decode: out = WoX · q, acc init = bout (f32-exact bias) ----
  u16x8 Q0 = *(const u16x8*)(Xt + myt * 64 + ((quad ^ (myt & 7)) << 3));
  u16x8 Q1 = *(const u16x8*)(Xt + myt * 64 + (((4 + quad) ^ (myt & 7)) << 3));
  float* ob0 = out + (size_t)b * DIMc * Tt + t0 + myt;
  #pragma unroll
  for (int mt = 0; mt < 16; ++mt) {
    const int c = mt * 16 + col;
    const u16* ar = WoX + c * 64;
    u16x8 A0 = *(const u16x8*)(ar + ((quad ^ (c & 7)) << 3));
    u16x8 A1 = *(const u16x8*)(ar + (((4 + quad) ^ (c & 7)) << 3));
    float4 bo = *(const float4*)(bout + mt * 16 + quad * 4);
    f32x4 a = {bo.x, bo.y, bo.z, bo.w};
    a = mfma16(A0, Q0, a);
    a = mfma16(A1, Q1, a);
    float* ob = ob0 + (size_t)(mt * 16 + quad * 4) * Tt;
    #pragma unroll
    for (int r = 0; r < 4; ++r) ob[(size_t)r * Tt] = a[r];
  }
}

extern "C" void kernel_launch(void* const* d_in, const int* in_sizes, int n_in,
                              void* d_out, int out_size, void* d_ws, size_t ws_size,
                              hipStream_t stream) {
  const float *in = nullptr, *cbp = nullptr, *rnd = nullptr, *bin = nullptr, *bout = nullptr;
  const float* w16[2] = {nullptr, nullptr}; int nw = 0;
  for (int i = 0; i < n_in; ++i) {
    switch (in_sizes[i]) {
      case 8388608: in  = (const float*)d_in[i]; break;
      case 65536:   cbp = (const float*)d_in[i]; break;
      case 2097152: rnd = (const float*)d_in[i]; break;
      case 64:      bin = (const float*)d_in[i]; break;
      case 256:     bout= (const float*)d_in[i]; break;
      case 16384:   if (nw < 2) w16[nw++] = (const float*)d_in[i]; break;
      default: break;
    }
  }
  if (!in)   in  = (const float*)d_in[0];
  if (!cbp)  cbp = (const float*)d_in[1];
  if (nw < 2) { w16[0] = (const float*)d_in[2]; w16[1] = (const float*)d_in[4]; }
  if (!bin)  bin = (const float*)d_in[3];
  if (!bout) bout = (const float*)d_in[5];
  if (!rnd)  rnd = (const float*)d_in[6];

  u16* wsu = (u16*)d_ws;
  nsvq_prep<<<64, 256, 0, stream>>>(cbp, w16[0], w16[1], wsu);
  nsvq_main<<<512, 256, 0, stream>>>(in, rnd, bin, bout, wsu, (float*)d_out);
}